// Round 1
// baseline (691.837 us; speedup 1.0000x reference)
//
#include <hip/hip_runtime.h>
#include <math.h>

#define TSEQ 2048
#define NB 4
#define DM 512
#define NH 8
#define HD 64

// ---------------- QKV GEMM + fused RoPE ----------------
// qkv[m][e] = sum_d x[m][d] * w[e][d];  e = three*512 + h*64 + d_h
// q,k get RoPE; scatter to q/k/v buffers laid out [n*NH+h][t][64]
__global__ __launch_bounds__(256) void qkv_rope_gemm(
    const float* __restrict__ x, const float* __restrict__ w,
    float* __restrict__ qb, float* __restrict__ kb, float* __restrict__ vb)
{
  __shared__ float As[16 * 68];
  __shared__ float Bs[16 * 68];
  const int tid = threadIdx.x;
  const int ty = tid >> 4, tx = tid & 15;
  const int m0 = blockIdx.x << 6;
  const int c0 = blockIdx.y << 6;
  const int lr = tid >> 2;   // 0..63
  const int lc = tid & 3;    // 0..3
  const float* ap = &x[(size_t)(m0 + lr) * DM + lc * 4];
  const float* bp = &w[(size_t)(c0 + lr) * DM + lc * 4];
  float acc[4][4] = {};
  for (int k0 = 0; k0 < DM; k0 += 16) {
    const float4 a4 = *(const float4*)(ap + k0);
    const float4 b4 = *(const float4*)(bp + k0);
    __syncthreads();
    As[(lc * 4 + 0) * 68 + lr] = a4.x; As[(lc * 4 + 1) * 68 + lr] = a4.y;
    As[(lc * 4 + 2) * 68 + lr] = a4.z; As[(lc * 4 + 3) * 68 + lr] = a4.w;
    Bs[(lc * 4 + 0) * 68 + lr] = b4.x; Bs[(lc * 4 + 1) * 68 + lr] = b4.y;
    Bs[(lc * 4 + 2) * 68 + lr] = b4.z; Bs[(lc * 4 + 3) * 68 + lr] = b4.w;
    __syncthreads();
#pragma unroll
    for (int kk = 0; kk < 16; kk++) {
      const float4 av = *(const float4*)&As[kk * 68 + (ty << 2)];
      const float4 bv = *(const float4*)&Bs[kk * 68 + (tx << 2)];
      const float aa[4] = {av.x, av.y, av.z, av.w};
      const float bb[4] = {bv.x, bv.y, bv.z, bv.w};
#pragma unroll
      for (int a = 0; a < 4; a++)
#pragma unroll
        for (int b = 0; b < 4; b++) acc[a][b] = fmaf(aa[a], bb[b], acc[a][b]);
    }
  }
  const int three = c0 >> 9;
  const int h = (c0 >> 6) & 7;
  if (three == 2) {
#pragma unroll
    for (int a = 0; a < 4; a++) {
      const int m = m0 + (ty << 2) + a;
      const int n = m >> 11, t = m & 2047;
      float4 o; o.x = acc[a][0]; o.y = acc[a][1]; o.z = acc[a][2]; o.w = acc[a][3];
      *(float4*)&vb[((size_t)(n * NH + h) * TSEQ + t) * HD + (tx << 2)] = o;
    }
  } else {
    float* dst = (three == 0) ? qb : kb;
    float invf[4];
#pragma unroll
    for (int b = 0; b < 4; b++) {
      const int d = (tx << 2) + b;
      const int i = d & 31;
      invf[b] = 1.0f / powf(10000.0f, (float)(2 * i) * (1.0f / 64.0f));
    }
    const bool hi = (tx >= 8);   // d >= 32 (uniform per thread)
#pragma unroll
    for (int a = 0; a < 4; a++) {
      const int m = m0 + (ty << 2) + a;
      const int n = m >> 11, t = m & 2047;
      float o[4];
#pragma unroll
      for (int b = 0; b < 4; b++) {
        const float partner = __shfl_xor(acc[a][b], 8, 64);  // value at d^32, same row
        float cs, sn;
        sincosf((float)t * invf[b], &sn, &cs);
        o[b] = hi ? fmaf(acc[a][b], cs, partner * sn)
                  : fmaf(acc[a][b], cs, -partner * sn);
      }
      float4 ov; ov.x = o[0]; ov.y = o[1]; ov.z = o[2]; ov.w = o[3];
      *(float4*)&dst[((size_t)(n * NH + h) * TSEQ + t) * HD + (tx << 2)] = ov;
    }
  }
}

// ---------------- windowed flash attention ----------------
// block: (q-tile of 64, n*NH+h). Q,K stored transposed [d][·] in LDS (conflict-free);
// score matrix P^T [j][q] aliases the K buffer (keeps static LDS < 64KB).
__global__ __launch_bounds__(256) void attn_win(
    const float* __restrict__ qb, const float* __restrict__ kb,
    const float* __restrict__ vb, float* __restrict__ ctx)
{
  __shared__ float Qs[64 * 64];   // [d][q], stride 64
  __shared__ float KP[64 * 68];   // Ks [d][j] then Ps [j][q], stride 68
  __shared__ float Vs[64 * 68];   // [j][d], stride 68
  __shared__ float m_s[64], l_s[64], al_s[64];
  const int tid = threadIdx.x;
  const int ty = tid >> 4, tx = tid & 15;
  const int nh = blockIdx.y;
  const int q0 = blockIdx.x << 6;
  const float* qp = qb + (size_t)nh * TSEQ * HD;
  const float* kp = kb + (size_t)nh * TSEQ * HD;
  const float* vp = vb + (size_t)nh * TSEQ * HD;
  const int lj = tid & 63, lw = tid >> 6;
  {
    const float4* src = (const float4*)&qp[(size_t)(q0 + lj) * HD];
#pragma unroll
    for (int c = 0; c < 4; c++) {
      const float4 v = src[lw * 4 + c];
      const int d = lw * 16 + c * 4;
      Qs[(d + 0) * 64 + lj] = v.x * 0.125f;
      Qs[(d + 1) * 64 + lj] = v.y * 0.125f;
      Qs[(d + 2) * 64 + lj] = v.z * 0.125f;
      Qs[(d + 3) * 64 + lj] = v.w * 0.125f;
    }
  }
  if (tid < 64) { m_s[tid] = -1e30f; l_s[tid] = 0.0f; }
  float acc[4][4] = {};
  const int kt0 = max(0, q0 - 127) >> 6;
  const int kt1 = min(TSEQ - 1, q0 + 63 + 128) >> 6;
  for (int kt = kt0; kt <= kt1; kt++) {
    const int j0 = kt << 6;
    float4 kreg[4], vreg[4];
    {
      const float4* ks = (const float4*)&kp[(size_t)(j0 + lj) * HD];
      const float4* vs = (const float4*)&vp[(size_t)(j0 + lj) * HD];
#pragma unroll
      for (int c = 0; c < 4; c++) { kreg[c] = ks[lw * 4 + c]; vreg[c] = vs[lw * 4 + c]; }
    }
    __syncthreads();   // prev-iter PV reads done; Q-fill visible on first iter
#pragma unroll
    for (int c = 0; c < 4; c++) {
      const int d = lw * 16 + c * 4;
      KP[(d + 0) * 68 + lj] = kreg[c].x;
      KP[(d + 1) * 68 + lj] = kreg[c].y;
      KP[(d + 2) * 68 + lj] = kreg[c].z;
      KP[(d + 3) * 68 + lj] = kreg[c].w;
      *(float4*)&Vs[lj * 68 + d] = vreg[c];
    }
    __syncthreads();
    // S = (Q*scale) K^T, 4x4 per thread
    float s[4][4] = {};
#pragma unroll
    for (int d = 0; d < 64; d++) {
      const float4 qv = *(const float4*)&Qs[d * 64 + (ty << 2)];
      const float4 kv = *(const float4*)&KP[d * 68 + (tx << 2)];
      const float qa[4] = {qv.x, qv.y, qv.z, qv.w};
      const float kk[4] = {kv.x, kv.y, kv.z, kv.w};
#pragma unroll
      for (int a = 0; a < 4; a++)
#pragma unroll
        for (int b = 0; b < 4; b++) s[a][b] = fmaf(qa[a], kk[b], s[a][b]);
    }
    __syncthreads();   // all K reads done; KP becomes P^T
#pragma unroll
    for (int b = 0; b < 4; b++) {
      const int jg = j0 + (tx << 2) + b;
      float4 col;
      {
        const int ig0 = q0 + (ty << 2);
        col.x = (jg >= ig0 + 0 - 127 && jg <= ig0 + 0 + 128) ? s[0][b] : -1e30f;
        col.y = (jg >= ig0 + 1 - 127 && jg <= ig0 + 1 + 128) ? s[1][b] : -1e30f;
        col.z = (jg >= ig0 + 2 - 127 && jg <= ig0 + 2 + 128) ? s[2][b] : -1e30f;
        col.w = (jg >= ig0 + 3 - 127 && jg <= ig0 + 3 + 128) ? s[3][b] : -1e30f;
      }
      *(float4*)&KP[(size_t)((tx << 2) + b) * 68 + (ty << 2)] = col;
    }
    __syncthreads();
    // online-softmax row pass: 4 lanes per query row
    {
      const int r = tid >> 2, part = tid & 3;
      float mx = -1e30f;
#pragma unroll
      for (int jj = 0; jj < 16; jj++)
        mx = fmaxf(mx, KP[(part * 16 + jj) * 68 + r]);
      mx = fmaxf(mx, __shfl_xor(mx, 1, 64));
      mx = fmaxf(mx, __shfl_xor(mx, 2, 64));
      const float m_old = m_s[r];
      const float m_new = fmaxf(m_old, mx);
      float lsum = 0.0f;
#pragma unroll
      for (int jj = 0; jj < 16; jj++) {
        const float sv = KP[(part * 16 + jj) * 68 + r];
        const float p = (sv > -1e29f) ? __expf(sv - m_new) : 0.0f;
        KP[(part * 16 + jj) * 68 + r] = p;
        lsum += p;
      }
      lsum += __shfl_xor(lsum, 1, 64);
      lsum += __shfl_xor(lsum, 2, 64);
      if (part == 0) {
        m_s[r] = m_new;
        l_s[r] = l_s[r] * __expf(m_old - m_new) + lsum;
        al_s[r] = __expf(m_old - m_new);
      }
    }
    __syncthreads();
    // rescale + PV
    {
      float al[4];
#pragma unroll
      for (int a = 0; a < 4; a++) al[a] = al_s[(ty << 2) + a];
#pragma unroll
      for (int a = 0; a < 4; a++)
#pragma unroll
        for (int b = 0; b < 4; b++) acc[a][b] *= al[a];
#pragma unroll
      for (int j = 0; j < 64; j++) {
        const float4 pv = *(const float4*)&KP[j * 68 + (ty << 2)];
        const float4 vv = *(const float4*)&Vs[j * 68 + (tx << 2)];
        const float pa[4] = {pv.x, pv.y, pv.z, pv.w};
        const float vv4[4] = {vv.x, vv.y, vv.z, vv.w};
#pragma unroll
        for (int a = 0; a < 4; a++)
#pragma unroll
          for (int b = 0; b < 4; b++) acc[a][b] = fmaf(pa[a], vv4[b], acc[a][b]);
      }
    }
  }
  const int n = nh >> 3, h = nh & 7;
  float linv[4];
#pragma unroll
  for (int a = 0; a < 4; a++) linv[a] = 1.0f / l_s[(ty << 2) + a];
#pragma unroll
  for (int a = 0; a < 4; a++) {
    const int t = q0 + (ty << 2) + a;
    float4 o;
    o.x = acc[a][0] * linv[a]; o.y = acc[a][1] * linv[a];
    o.z = acc[a][2] * linv[a]; o.w = acc[a][3] * linv[a];
    *(float4*)&ctx[((size_t)n * TSEQ + t) * DM + h * HD + (tx << 2)] = o;
  }
}

// ---------------- output projection + bias ----------------
__global__ __launch_bounds__(256) void out_proj_gemm(
    const float* __restrict__ ctx, const float* __restrict__ w,
    const float* __restrict__ bias, float* __restrict__ out)
{
  __shared__ float As[16 * 68];
  __shared__ float Bs[16 * 68];
  const int tid = threadIdx.x;
  const int ty = tid >> 4, tx = tid & 15;
  const int m0 = blockIdx.x << 6;
  const int c0 = blockIdx.y << 6;
  const int lr = tid >> 2, lc = tid & 3;
  const float* ap = &ctx[(size_t)(m0 + lr) * DM + lc * 4];
  const float* bp = &w[(size_t)(c0 + lr) * DM + lc * 4];
  float acc[4][4] = {};
  for (int k0 = 0; k0 < DM; k0 += 16) {
    const float4 a4 = *(const float4*)(ap + k0);
    const float4 b4 = *(const float4*)(bp + k0);
    __syncthreads();
    As[(lc * 4 + 0) * 68 + lr] = a4.x; As[(lc * 4 + 1) * 68 + lr] = a4.y;
    As[(lc * 4 + 2) * 68 + lr] = a4.z; As[(lc * 4 + 3) * 68 + lr] = a4.w;
    Bs[(lc * 4 + 0) * 68 + lr] = b4.x; Bs[(lc * 4 + 1) * 68 + lr] = b4.y;
    Bs[(lc * 4 + 2) * 68 + lr] = b4.z; Bs[(lc * 4 + 3) * 68 + lr] = b4.w;
    __syncthreads();
#pragma unroll
    for (int kk = 0; kk < 16; kk++) {
      const float4 av = *(const float4*)&As[kk * 68 + (ty << 2)];
      const float4 bv = *(const float4*)&Bs[kk * 68 + (tx << 2)];
      const float aa[4] = {av.x, av.y, av.z, av.w};
      const float bb[4] = {bv.x, bv.y, bv.z, bv.w};
#pragma unroll
      for (int a = 0; a < 4; a++)
#pragma unroll
        for (int b = 0; b < 4; b++) acc[a][b] = fmaf(aa[a], bb[b], acc[a][b]);
    }
  }
  const float4 bv4 = *(const float4*)&bias[c0 + (tx << 2)];
  const float bb[4] = {bv4.x, bv4.y, bv4.z, bv4.w};
#pragma unroll
  for (int a = 0; a < 4; a++) {
    const int m = m0 + (ty << 2) + a;
    float4 o;
    o.x = acc[a][0] + bb[0]; o.y = acc[a][1] + bb[1];
    o.z = acc[a][2] + bb[2]; o.w = acc[a][3] + bb[3];
    *(float4*)&out[(size_t)m * DM + c0 + (tx << 2)] = o;
  }
}

extern "C" void kernel_launch(void* const* d_in, const int* in_sizes, int n_in,
                              void* d_out, int out_size, void* d_ws, size_t ws_size,
                              hipStream_t stream) {
  const float* x    = (const float*)d_in[0];
  const float* wqkv = (const float*)d_in[1];
  const float* ow   = (const float*)d_in[2];
  const float* ob   = (const float*)d_in[3];
  float* ws = (float*)d_ws;
  const size_t SZ = (size_t)NB * NH * TSEQ * HD;  // 4,194,304 floats
  float* qbuf = ws;
  float* kbuf = ws + SZ;
  float* vbuf = ws + 2 * SZ;
  float* cbuf = ws + 3 * SZ;
  qkv_rope_gemm<<<dim3(128, 24), 256, 0, stream>>>(x, wqkv, qbuf, kbuf, vbuf);
  attn_win<<<dim3(32, 32), 256, 0, stream>>>(qbuf, kbuf, vbuf, cbuf);
  out_proj_gemm<<<dim3(128, 8), 256, 0, stream>>>(cbuf, ow, ob, (float*)d_out);
}

// Round 2
// 336.059 us; speedup vs baseline: 2.0587x; 2.0587x over previous
//
#include <hip/hip_runtime.h>
#include <math.h>

#define TSEQ 2048
#define NB 4
#define DM 512
#define NH 8
#define HD 64

typedef _Float16 half8 __attribute__((ext_vector_type(8)));
typedef _Float16 half4 __attribute__((ext_vector_type(4)));
typedef float floatx4 __attribute__((ext_vector_type(4)));

// ---------------- QKV GEMM + fused RoPE (fp32, unchanged) ----------------
__global__ __launch_bounds__(256) void qkv_rope_gemm(
    const float* __restrict__ x, const float* __restrict__ w,
    float* __restrict__ qb, float* __restrict__ kb, float* __restrict__ vb)
{
  __shared__ float As[16 * 68];
  __shared__ float Bs[16 * 68];
  const int tid = threadIdx.x;
  const int ty = tid >> 4, tx = tid & 15;
  const int m0 = blockIdx.x << 6;
  const int c0 = blockIdx.y << 6;
  const int lr = tid >> 2;
  const int lc = tid & 3;
  const float* ap = &x[(size_t)(m0 + lr) * DM + lc * 4];
  const float* bp = &w[(size_t)(c0 + lr) * DM + lc * 4];
  float acc[4][4] = {};
  for (int k0 = 0; k0 < DM; k0 += 16) {
    const float4 a4 = *(const float4*)(ap + k0);
    const float4 b4 = *(const float4*)(bp + k0);
    __syncthreads();
    As[(lc * 4 + 0) * 68 + lr] = a4.x; As[(lc * 4 + 1) * 68 + lr] = a4.y;
    As[(lc * 4 + 2) * 68 + lr] = a4.z; As[(lc * 4 + 3) * 68 + lr] = a4.w;
    Bs[(lc * 4 + 0) * 68 + lr] = b4.x; Bs[(lc * 4 + 1) * 68 + lr] = b4.y;
    Bs[(lc * 4 + 2) * 68 + lr] = b4.z; Bs[(lc * 4 + 3) * 68 + lr] = b4.w;
    __syncthreads();
#pragma unroll
    for (int kk = 0; kk < 16; kk++) {
      const float4 av = *(const float4*)&As[kk * 68 + (ty << 2)];
      const float4 bv = *(const float4*)&Bs[kk * 68 + (tx << 2)];
      const float aa[4] = {av.x, av.y, av.z, av.w};
      const float bb[4] = {bv.x, bv.y, bv.z, bv.w};
#pragma unroll
      for (int a = 0; a < 4; a++)
#pragma unroll
        for (int b = 0; b < 4; b++) acc[a][b] = fmaf(aa[a], bb[b], acc[a][b]);
    }
  }
  const int three = c0 >> 9;
  const int h = (c0 >> 6) & 7;
  if (three == 2) {
#pragma unroll
    for (int a = 0; a < 4; a++) {
      const int m = m0 + (ty << 2) + a;
      const int n = m >> 11, t = m & 2047;
      float4 o; o.x = acc[a][0]; o.y = acc[a][1]; o.z = acc[a][2]; o.w = acc[a][3];
      *(float4*)&vb[((size_t)(n * NH + h) * TSEQ + t) * HD + (tx << 2)] = o;
    }
  } else {
    float* dst = (three == 0) ? qb : kb;
    float invf[4];
#pragma unroll
    for (int b = 0; b < 4; b++) {
      const int d = (tx << 2) + b;
      const int i = d & 31;
      invf[b] = 1.0f / powf(10000.0f, (float)(2 * i) * (1.0f / 64.0f));
    }
    const bool hi = (tx >= 8);
#pragma unroll
    for (int a = 0; a < 4; a++) {
      const int m = m0 + (ty << 2) + a;
      const int n = m >> 11, t = m & 2047;
      float o[4];
#pragma unroll
      for (int b = 0; b < 4; b++) {
        const float partner = __shfl_xor(acc[a][b], 8, 64);
        float cs, sn;
        sincosf((float)t * invf[b], &sn, &cs);
        o[b] = hi ? fmaf(acc[a][b], cs, partner * sn)
                  : fmaf(acc[a][b], cs, -partner * sn);
      }
      float4 ov; ov.x = o[0]; ov.y = o[1]; ov.z = o[2]; ov.w = o[3];
      *(float4*)&dst[((size_t)(n * NH + h) * TSEQ + t) * HD + (tx << 2)] = ov;
    }
  }
}

// ---------------- windowed flash attention, f16 MFMA ----------------
// Block: 64 queries x (n,h). 4 waves, wave owns 16 queries (i = wv*16 + col).
// Per 64-key tile: S^T = K·Q^T via mfma (C-layout: col=query), softmax state in
// registers, P -> LDS [i][j] (b64 writes), PV: A=P (b128), B=V^T staged [d][j] (b128).
__global__ __launch_bounds__(256, 4) void attn_win_mfma(
    const float* __restrict__ qb, const float* __restrict__ kb,
    const float* __restrict__ vb, float* __restrict__ ctx)
{
  __shared__ __align__(16) char smem[36864];
  _Float16* Ks = (_Float16*)smem;              // [64][72] j-major
  _Float16* Qs = (_Float16*)(smem + 9216);     // [64][72] i-major (scaled)
  _Float16* Vt = (_Float16*)(smem + 18432);    // [64][72] d-major (transposed)
  _Float16* Ps = (_Float16*)(smem + 27648);    // [64][72] i-major
  float* Osh = (float*)smem;                   // [64][68] aliases Ks+Qs post-loop

  const int tid = threadIdx.x;
  const int wv = tid >> 6;
  const int lane = tid & 63;
  const int quad = lane >> 4;
  const int col = lane & 15;
  const int nh = blockIdx.y;
  const int q0 = blockIdx.x << 6;
  const float* qp = qb + (size_t)nh * TSEQ * HD;
  const float* kp = kb + (size_t)nh * TSEQ * HD;
  const float* vp = vb + (size_t)nh * TSEQ * HD;

  // stage Q (scaled by 1/8) as f16 [i][d]
  {
    const int i = tid >> 2, dc = (tid & 3) << 4;
    float qq[16];
#pragma unroll
    for (int r = 0; r < 4; r++)
      *(float4*)&qq[r * 4] = *(const float4*)&qp[(size_t)(q0 + i) * HD + dc + r * 4];
    half8 h0, h1;
#pragma unroll
    for (int e = 0; e < 8; e++) { h0[e] = (_Float16)(qq[e] * 0.125f); h1[e] = (_Float16)(qq[8 + e] * 0.125f); }
    *(half8*)&Qs[i * 72 + dc] = h0;
    *(half8*)&Qs[i * 72 + dc + 8] = h1;
  }
  __syncthreads();
  const int i_row = (wv << 4) + col;
  const int ig = q0 + i_row;
  const half8 qf0 = *(const half8*)&Qs[i_row * 72 + (quad << 3)];
  const half8 qf1 = *(const half8*)&Qs[i_row * 72 + 32 + (quad << 3)];

  float m_i = -1e30f, l_i = 0.0f;
  floatx4 accO[4] = {{0.f,0.f,0.f,0.f},{0.f,0.f,0.f,0.f},{0.f,0.f,0.f,0.f},{0.f,0.f,0.f,0.f}};

  const int kt0 = max(0, q0 - 127) >> 6;
  const int kt1 = min(TSEQ - 1, q0 + 191) >> 6;
  for (int kt = kt0; kt <= kt1; kt++) {
    const int j0 = kt << 6;
    // global prefetch (before barrier)
    const int jr = tid >> 2, kdc = (tid & 3) << 4;
    float kk[16];
#pragma unroll
    for (int r = 0; r < 4; r++)
      *(float4*)&kk[r * 4] = *(const float4*)&kp[(size_t)(j0 + jr) * HD + kdc + r * 4];
    const int vj4 = (tid & 15) << 2, vdc = (tid >> 4) << 2;
    float vv[4][4];
#pragma unroll
    for (int r = 0; r < 4; r++)
      *(float4*)&vv[r][0] = *(const float4*)&vp[(size_t)(j0 + vj4 + r) * HD + vdc];
    __syncthreads();   // previous iteration's LDS reads complete
    {
      half8 h0, h1;
#pragma unroll
      for (int e = 0; e < 8; e++) { h0[e] = (_Float16)kk[e]; h1[e] = (_Float16)kk[8 + e]; }
      *(half8*)&Ks[jr * 72 + kdc] = h0;
      *(half8*)&Ks[jr * 72 + kdc + 8] = h1;
#pragma unroll
      for (int c = 0; c < 4; c++) {
        half4 h = {(_Float16)vv[0][c], (_Float16)vv[1][c], (_Float16)vv[2][c], (_Float16)vv[3][c]};
        *(half4*)&Vt[(vdc + c) * 72 + vj4] = h;
      }
    }
    __syncthreads();   // staging visible

    // S^T[j][i]: A = K rows, B = Q^T. C-layout: row=j_local, col=i(=our query)
    floatx4 S[4];
#pragma unroll
    for (int js = 0; js < 4; js++) {
      const half8 a0 = *(const half8*)&Ks[((js << 4) + col) * 72 + (quad << 3)];
      const half8 a1 = *(const half8*)&Ks[((js << 4) + col) * 72 + 32 + (quad << 3)];
      floatx4 c = {0.f, 0.f, 0.f, 0.f};
      c = __builtin_amdgcn_mfma_f32_16x16x32_f16(a0, qf0, c, 0, 0, 0);
      c = __builtin_amdgcn_mfma_f32_16x16x32_f16(a1, qf1, c, 0, 0, 0);
      S[js] = c;
    }
    // mask + online softmax (state per-lane: query = i_row, uniform across quads)
    float mx = -1e30f;
#pragma unroll
    for (int js = 0; js < 4; js++)
#pragma unroll
      for (int r = 0; r < 4; r++) {
        const int jg = j0 + (js << 4) + (quad << 2) + r;
        const bool valid = (jg >= ig - 127) && (jg <= ig + 128);
        const float s = valid ? S[js][r] : -INFINITY;
        S[js][r] = s;
        mx = fmaxf(mx, s);
      }
    mx = fmaxf(mx, __shfl_xor(mx, 16, 64));
    mx = fmaxf(mx, __shfl_xor(mx, 32, 64));
    const float m_new = fmaxf(m_i, mx);
    const float alpha = __expf(m_i - m_new);
    float lsum = 0.f;
#pragma unroll
    for (int js = 0; js < 4; js++) {
      half4 ph;
#pragma unroll
      for (int r = 0; r < 4; r++) {
        const float p = __expf(S[js][r] - m_new);
        lsum += p;
        ph[r] = (_Float16)p;
      }
      *(half4*)&Ps[i_row * 72 + (js << 4) + (quad << 2)] = ph;
    }
    lsum += __shfl_xor(lsum, 16, 64);
    lsum += __shfl_xor(lsum, 32, 64);
    l_i = l_i * alpha + lsum;
    m_i = m_new;
    // rescale O accumulator: its rows are queries wv*16+quad*4+r -> fetch alpha per r
    float a4[4];
#pragma unroll
    for (int r = 0; r < 4; r++) a4[r] = __shfl(alpha, (quad << 2) + r, 64);
#pragma unroll
    for (int d4 = 0; d4 < 4; d4++)
#pragma unroll
      for (int r = 0; r < 4; r++) accO[d4][r] *= a4[r];
    // PV: O[i][d] += P[i][j] V[j][d];  A = P (b128 from Ps), B = V (b128 from Vt)
    const half8 pa0 = *(const half8*)&Ps[i_row * 72 + (quad << 3)];
    const half8 pa1 = *(const half8*)&Ps[i_row * 72 + 32 + (quad << 3)];
#pragma unroll
    for (int d4 = 0; d4 < 4; d4++) {
      const half8 vb0 = *(const half8*)&Vt[((d4 << 4) + col) * 72 + (quad << 3)];
      const half8 vb1 = *(const half8*)&Vt[((d4 << 4) + col) * 72 + 32 + (quad << 3)];
      accO[d4] = __builtin_amdgcn_mfma_f32_16x16x32_f16(pa0, vb0, accO[d4], 0, 0, 0);
      accO[d4] = __builtin_amdgcn_mfma_f32_16x16x32_f16(pa1, vb1, accO[d4], 0, 0, 0);
    }
  }
  __syncthreads();   // all waves done with Ks/Qs before Osh alias writes
  {
    const float linv = 1.0f / l_i;
    float l4[4];
#pragma unroll
    for (int r = 0; r < 4; r++) l4[r] = __shfl(linv, (quad << 2) + r, 64);
#pragma unroll
    for (int d4 = 0; d4 < 4; d4++)
#pragma unroll
      for (int r = 0; r < 4; r++)
        Osh[((wv << 4) + (quad << 2) + r) * 68 + (d4 << 4) + col] = accO[d4][r] * l4[r];
  }
  __syncthreads();
  {
    const int n = nh >> 3, h = nh & 7;
    const int oi = tid >> 2, odc = (tid & 3) << 4;
    float* dst = &ctx[((size_t)n * TSEQ + q0 + oi) * DM + h * HD + odc];
#pragma unroll
    for (int c = 0; c < 4; c++)
      *(float4*)&dst[c * 4] = *(const float4*)&Osh[oi * 68 + odc + c * 4];
  }
}

// ---------------- output projection + bias (fp32, unchanged) ----------------
__global__ __launch_bounds__(256) void out_proj_gemm(
    const float* __restrict__ ctx, const float* __restrict__ w,
    const float* __restrict__ bias, float* __restrict__ out)
{
  __shared__ float As[16 * 68];
  __shared__ float Bs[16 * 68];
  const int tid = threadIdx.x;
  const int ty = tid >> 4, tx = tid & 15;
  const int m0 = blockIdx.x << 6;
  const int c0 = blockIdx.y << 6;
  const int lr = tid >> 2, lc = tid & 3;
  const float* ap = &ctx[(size_t)(m0 + lr) * DM + lc * 4];
  const float* bp = &w[(size_t)(c0 + lr) * DM + lc * 4];
  float acc[4][4] = {};
  for (int k0 = 0; k0 < DM; k0 += 16) {
    const float4 a4 = *(const float4*)(ap + k0);
    const float4 b4 = *(const float4*)(bp + k0);
    __syncthreads();
    As[(lc * 4 + 0) * 68 + lr] = a4.x; As[(lc * 4 + 1) * 68 + lr] = a4.y;
    As[(lc * 4 + 2) * 68 + lr] = a4.z; As[(lc * 4 + 3) * 68 + lr] = a4.w;
    Bs[(lc * 4 + 0) * 68 + lr] = b4.x; Bs[(lc * 4 + 1) * 68 + lr] = b4.y;
    Bs[(lc * 4 + 2) * 68 + lr] = b4.z; Bs[(lc * 4 + 3) * 68 + lr] = b4.w;
    __syncthreads();
#pragma unroll
    for (int kk = 0; kk < 16; kk++) {
      const float4 av = *(const float4*)&As[kk * 68 + (ty << 2)];
      const float4 bv = *(const float4*)&Bs[kk * 68 + (tx << 2)];
      const float aa[4] = {av.x, av.y, av.z, av.w};
      const float bb[4] = {bv.x, bv.y, bv.z, bv.w};
#pragma unroll
      for (int a = 0; a < 4; a++)
#pragma unroll
        for (int b = 0; b < 4; b++) acc[a][b] = fmaf(aa[a], bb[b], acc[a][b]);
    }
  }
  const float4 bv4 = *(const float4*)&bias[c0 + (tx << 2)];
  const float bb[4] = {bv4.x, bv4.y, bv4.z, bv4.w};
#pragma unroll
  for (int a = 0; a < 4; a++) {
    const int m = m0 + (ty << 2) + a;
    float4 o;
    o.x = acc[a][0] + bb[0]; o.y = acc[a][1] + bb[1];
    o.z = acc[a][2] + bb[2]; o.w = acc[a][3] + bb[3];
    *(float4*)&out[(size_t)m * DM + c0 + (tx << 2)] = o;
  }
}

extern "C" void kernel_launch(void* const* d_in, const int* in_sizes, int n_in,
                              void* d_out, int out_size, void* d_ws, size_t ws_size,
                              hipStream_t stream) {
  const float* x    = (const float*)d_in[0];
  const float* wqkv = (const float*)d_in[1];
  const float* ow   = (const float*)d_in[2];
  const float* ob   = (const float*)d_in[3];
  float* ws = (float*)d_ws;
  const size_t SZ = (size_t)NB * NH * TSEQ * HD;
  float* qbuf = ws;
  float* kbuf = ws + SZ;
  float* vbuf = ws + 2 * SZ;
  float* cbuf = ws + 3 * SZ;
  qkv_rope_gemm<<<dim3(128, 24), 256, 0, stream>>>(x, wqkv, qbuf, kbuf, vbuf);
  attn_win_mfma<<<dim3(32, 32), 256, 0, stream>>>(qbuf, kbuf, vbuf, cbuf);
  out_proj_gemm<<<dim3(128, 8), 256, 0, stream>>>(cbuf, ow, ob, (float*)d_out);
}

// Round 4
// 155.028 us; speedup vs baseline: 4.4626x; 2.1677x over previous
//
#include <hip/hip_runtime.h>
#include <math.h>

#define TSEQ 2048
#define NB 4
#define DM 512
#define NH 8
#define HD 64

typedef _Float16 half8 __attribute__((ext_vector_type(8)));
typedef _Float16 half4 __attribute__((ext_vector_type(4)));
typedef float floatx4 __attribute__((ext_vector_type(4)));

// ---------------- zero-init workspace (restores validation-time initial state) ----
__global__ void zero_ws(float4* __restrict__ p, int n16) {
  const float4 z = make_float4(0.f, 0.f, 0.f, 0.f);
  for (int i = blockIdx.x * blockDim.x + threadIdx.x; i < n16; i += gridDim.x * blockDim.x)
    p[i] = z;
}

// ---------------- f32 -> f16 conversion prepass ----------------
__global__ void cvt_f16(const float* __restrict__ src, _Float16* __restrict__ dst, int n8) {
  const int i = blockIdx.x * blockDim.x + threadIdx.x;
  if (i >= n8) return;
  const float4 a = ((const float4*)src)[2 * i];
  const float4 b = ((const float4*)src)[2 * i + 1];
  half8 h;
  h[0] = (_Float16)a.x; h[1] = (_Float16)a.y; h[2] = (_Float16)a.z; h[3] = (_Float16)a.w;
  h[4] = (_Float16)b.x; h[5] = (_Float16)b.y; h[6] = (_Float16)b.z; h[7] = (_Float16)b.w;
  *(half8*)&dst[(size_t)i * 8] = h;
}

// ---------------- RoPE cos/sin table: [t][i] -> (cos, sin) ----------------
__global__ void rope_tab(float2* __restrict__ tab) {
  const int id = blockIdx.x * 256 + threadIdx.x;   // 0..65535
  const int t = id >> 5, i = id & 31;
  const float invf = powf(10000.0f, -(float)(2 * i) * (1.0f / 64.0f));
  float s, c;
  sincosf((float)t * invf, &s, &c);
  tab[id] = make_float2(c, s);
}

// ---------------- QKV GEMM (f16 MFMA) + fused RoPE ----------------
__global__ __launch_bounds__(256) void qkv_gemm_mfma(
    const _Float16* __restrict__ A, const _Float16* __restrict__ B,
    const float2* __restrict__ rope,
    _Float16* __restrict__ qb, _Float16* __restrict__ kb, _Float16* __restrict__ vT)
{
  __shared__ _Float16 As[128 * 40];
  __shared__ _Float16 Bs[128 * 40];
  const int tid = threadIdx.x;
  const int wv = tid >> 6, lane = tid & 63, quad = lane >> 4, col = lane & 15;
  const int wm = wv >> 1, we = wv & 1;
  const int m0 = blockIdx.x << 7, c0 = blockIdx.y << 7;
  const int sr = tid >> 1, sc = (tid & 1) << 4;
  const _Float16* ap = &A[(size_t)(m0 + sr) * DM + sc];
  const _Float16* bp = &B[(size_t)(c0 + sr) * DM + sc];
  floatx4 acc[4][4] = {};   // [mt][et]
  for (int k0 = 0; k0 < DM; k0 += 32) {
    const half8 a0 = *(const half8*)(ap + k0);
    const half8 a1 = *(const half8*)(ap + k0 + 8);
    const half8 b0 = *(const half8*)(bp + k0);
    const half8 b1 = *(const half8*)(bp + k0 + 8);
    __syncthreads();
    *(half8*)&As[sr * 40 + sc] = a0;
    *(half8*)&As[sr * 40 + sc + 8] = a1;
    *(half8*)&Bs[sr * 40 + sc] = b0;
    *(half8*)&Bs[sr * 40 + sc + 8] = b1;
    __syncthreads();
    half8 af[4], bf[4];
#pragma unroll
    for (int mt = 0; mt < 4; mt++)
      af[mt] = *(const half8*)&As[(wm * 64 + mt * 16 + col) * 40 + quad * 8];
#pragma unroll
    for (int et = 0; et < 4; et++)
      bf[et] = *(const half8*)&Bs[(we * 64 + et * 16 + col) * 40 + quad * 8];
#pragma unroll
    for (int mt = 0; mt < 4; mt++)
#pragma unroll
      for (int et = 0; et < 4; et++)
        acc[mt][et] = __builtin_amdgcn_mfma_f32_16x16x32_f16(af[mt], bf[et], acc[mt][et], 0, 0, 0);
  }
  const int eidx = (c0 >> 6) + we;            // 0..23, wave-uniform
  const int three = eidx >> 3, h = eidx & 7;
  const int mbase = m0 + wm * 64 + quad * 4;
  if (three == 2) {
#pragma unroll
    for (int mt = 0; mt < 4; mt++) {
      const int m = mbase + mt * 16;
      const int n = m >> 11, t = m & 2047;
#pragma unroll
      for (int et = 0; et < 4; et++) {
        const int dh = et * 16 + col;
        half4 hv;
#pragma unroll
        for (int r = 0; r < 4; r++) hv[r] = (_Float16)acc[mt][et][r];
        *(half4*)&vT[(size_t)(n * NH + h) * HD * TSEQ + (size_t)dh * TSEQ + t] = hv;
      }
    }
  } else {
    _Float16* dst = three ? kb : qb;
    const float scl = three ? 1.0f : 0.125f;
#pragma unroll
    for (int mt = 0; mt < 4; mt++)
#pragma unroll
      for (int r = 0; r < 4; r++) {
        const int m = mbase + mt * 16 + r;
        const int n = m >> 11, t = m & 2047;
#pragma unroll
        for (int et = 0; et < 4; et++) {
          const int i = ((et & 1) << 4) + col;
          const float2 cs = rope[t * 32 + i];
          const float v = acc[mt][et][r];
          const float v2 = acc[mt][et ^ 2][r];
          const float o = (et < 2) ? (v * cs.x - v2 * cs.y) : (v * cs.x + v2 * cs.y);
          dst[((size_t)(n * NH + h) * TSEQ + t) * HD + et * 16 + col] = (_Float16)(o * scl);
        }
      }
  }
}

// ---------------- windowed flash attention, f16 MFMA, f16 I/O ----------------
__global__ __launch_bounds__(256, 4) void attn_win_mfma(
    const _Float16* __restrict__ qb, const _Float16* __restrict__ kb,
    const _Float16* __restrict__ vT, _Float16* __restrict__ ctx)
{
  __shared__ __align__(16) char smem[36864];
  _Float16* Ks = (_Float16*)smem;              // [64][72] j-major
  _Float16* Vt = (_Float16*)(smem + 9216);     // [64][72] d-major (from vT global)
  _Float16* Ps = (_Float16*)(smem + 18432);    // [64][72] i-major
  _Float16* Osh = (_Float16*)(smem + 27648);   // [64][72] dedicated (no alias)

  const int tid = threadIdx.x;
  const int wv = tid >> 6;
  const int lane = tid & 63;
  const int quad = lane >> 4;
  const int col = lane & 15;
  const int nh = blockIdx.y;
  const int q0 = blockIdx.x << 6;
  const _Float16* qp = qb + (size_t)nh * TSEQ * HD;
  const _Float16* kp = kb + (size_t)nh * TSEQ * HD;
  const _Float16* vp = vT + (size_t)nh * HD * TSEQ;

  const int i_row = (wv << 4) + col;
  const int ig = q0 + i_row;
  // Q frags direct from global (pre-scaled by 1/8 in qkv epilogue)
  const half8 qf0 = *(const half8*)&qp[(size_t)ig * HD + (quad << 3)];
  const half8 qf1 = *(const half8*)&qp[(size_t)ig * HD + 32 + (quad << 3)];

  float m_i = -1e30f, l_i = 0.0f;
  floatx4 accO[4] = {};

  const int kt0 = max(0, q0 - 127) >> 6;
  const int kt1 = min(TSEQ - 1, q0 + 191) >> 6;
  const int kr = tid >> 2, kc = (tid & 3) << 4;    // K: row j, col d
  const int vd = tid >> 2, vc = (tid & 3) << 4;    // V^T: row d, col j
  for (int kt = kt0; kt <= kt1; kt++) {
    const int j0 = kt << 6;
    const half8 k0_ = *(const half8*)&kp[(size_t)(j0 + kr) * HD + kc];
    const half8 k1_ = *(const half8*)&kp[(size_t)(j0 + kr) * HD + kc + 8];
    const half8 v0_ = *(const half8*)&vp[(size_t)vd * TSEQ + j0 + vc];
    const half8 v1_ = *(const half8*)&vp[(size_t)vd * TSEQ + j0 + vc + 8];
    __syncthreads();   // previous iteration's LDS reads complete
    *(half8*)&Ks[kr * 72 + kc] = k0_;
    *(half8*)&Ks[kr * 72 + kc + 8] = k1_;
    *(half8*)&Vt[vd * 72 + vc] = v0_;
    *(half8*)&Vt[vd * 72 + vc + 8] = v1_;
    __syncthreads();   // staging visible

    // S^T[j][i]: A = K rows, B = Q^T. C-layout: row=j_local, col=i(=our query)
    floatx4 S[4];
#pragma unroll
    for (int js = 0; js < 4; js++) {
      const half8 a0 = *(const half8*)&Ks[((js << 4) + col) * 72 + (quad << 3)];
      const half8 a1 = *(const half8*)&Ks[((js << 4) + col) * 72 + 32 + (quad << 3)];
      floatx4 c = {0.f, 0.f, 0.f, 0.f};
      c = __builtin_amdgcn_mfma_f32_16x16x32_f16(a0, qf0, c, 0, 0, 0);
      c = __builtin_amdgcn_mfma_f32_16x16x32_f16(a1, qf1, c, 0, 0, 0);
      S[js] = c;
    }
    float mx = -1e30f;
#pragma unroll
    for (int js = 0; js < 4; js++)
#pragma unroll
      for (int r = 0; r < 4; r++) {
        const int jg = j0 + (js << 4) + (quad << 2) + r;
        const bool valid = (jg >= ig - 127) && (jg <= ig + 128);
        const float s = valid ? S[js][r] : -INFINITY;
        S[js][r] = s;
        mx = fmaxf(mx, s);
      }
    mx = fmaxf(mx, __shfl_xor(mx, 16, 64));
    mx = fmaxf(mx, __shfl_xor(mx, 32, 64));
    const float m_new = fmaxf(m_i, mx);
    const float alpha = __expf(m_i - m_new);
    float lsum = 0.f;
#pragma unroll
    for (int js = 0; js < 4; js++) {
      half4 ph;
#pragma unroll
      for (int r = 0; r < 4; r++) {
        const float p = __expf(S[js][r] - m_new);
        lsum += p;
        ph[r] = (_Float16)p;
      }
      *(half4*)&Ps[i_row * 72 + (js << 4) + (quad << 2)] = ph;
    }
    lsum += __shfl_xor(lsum, 16, 64);
    lsum += __shfl_xor(lsum, 32, 64);
    l_i = l_i * alpha + lsum;
    m_i = m_new;
    float a4[4];
#pragma unroll
    for (int r = 0; r < 4; r++) a4[r] = __shfl(alpha, (quad << 2) + r, 64);
#pragma unroll
    for (int d4 = 0; d4 < 4; d4++)
#pragma unroll
      for (int r = 0; r < 4; r++) accO[d4][r] *= a4[r];
    __syncthreads();   // Ps cross-lane handoff made block-safe
    const half8 pa0 = *(const half8*)&Ps[i_row * 72 + (quad << 3)];
    const half8 pa1 = *(const half8*)&Ps[i_row * 72 + 32 + (quad << 3)];
#pragma unroll
    for (int d4 = 0; d4 < 4; d4++) {
      const half8 vb0 = *(const half8*)&Vt[((d4 << 4) + col) * 72 + (quad << 3)];
      const half8 vb1 = *(const half8*)&Vt[((d4 << 4) + col) * 72 + 32 + (quad << 3)];
      accO[d4] = __builtin_amdgcn_mfma_f32_16x16x32_f16(pa0, vb0, accO[d4], 0, 0, 0);
      accO[d4] = __builtin_amdgcn_mfma_f32_16x16x32_f16(pa1, vb1, accO[d4], 0, 0, 0);
    }
  }
  {
    const float linv = 1.0f / l_i;
    float l4[4];
#pragma unroll
    for (int r = 0; r < 4; r++) l4[r] = __shfl(linv, (quad << 2) + r, 64);
#pragma unroll
    for (int d4 = 0; d4 < 4; d4++)
#pragma unroll
      for (int r = 0; r < 4; r++)
        Osh[((wv << 4) + (quad << 2) + r) * 72 + (d4 << 4) + col] = (_Float16)(accO[d4][r] * l4[r]);
  }
  __syncthreads();
  {
    const int n = nh >> 3, h = nh & 7;
    const int oi = tid >> 2, oc = (tid & 3) << 4;
    _Float16* dst = &ctx[((size_t)n * TSEQ + q0 + oi) * DM + h * HD + oc];
    *(half8*)&dst[0] = *(const half8*)&Osh[oi * 72 + oc];
    *(half8*)&dst[8] = *(const half8*)&Osh[oi * 72 + oc + 8];
  }
}

// ---------------- output projection (f16 MFMA) + bias, f32 out ----------------
__global__ __launch_bounds__(256) void out_gemm_mfma(
    const _Float16* __restrict__ A, const _Float16* __restrict__ B,
    const float* __restrict__ bias, float* __restrict__ out)
{
  __shared__ _Float16 As[128 * 40];
  __shared__ _Float16 Bs[128 * 40];
  const int tid = threadIdx.x;
  const int wv = tid >> 6, lane = tid & 63, quad = lane >> 4, col = lane & 15;
  const int wm = wv >> 1, we = wv & 1;
  const int m0 = blockIdx.x << 7, c0 = blockIdx.y << 7;
  const int sr = tid >> 1, sc = (tid & 1) << 4;
  const _Float16* ap = &A[(size_t)(m0 + sr) * DM + sc];
  const _Float16* bp = &B[(size_t)(c0 + sr) * DM + sc];
  floatx4 acc[4][4] = {};
  for (int k0 = 0; k0 < DM; k0 += 32) {
    const half8 a0 = *(const half8*)(ap + k0);
    const half8 a1 = *(const half8*)(ap + k0 + 8);
    const half8 b0 = *(const half8*)(bp + k0);
    const half8 b1 = *(const half8*)(bp + k0 + 8);
    __syncthreads();
    *(half8*)&As[sr * 40 + sc] = a0;
    *(half8*)&As[sr * 40 + sc + 8] = a1;
    *(half8*)&Bs[sr * 40 + sc] = b0;
    *(half8*)&Bs[sr * 40 + sc + 8] = b1;
    __syncthreads();
    half8 af[4], bf[4];
#pragma unroll
    for (int mt = 0; mt < 4; mt++)
      af[mt] = *(const half8*)&As[(wm * 64 + mt * 16 + col) * 40 + quad * 8];
#pragma unroll
    for (int et = 0; et < 4; et++)
      bf[et] = *(const half8*)&Bs[(we * 64 + et * 16 + col) * 40 + quad * 8];
#pragma unroll
    for (int mt = 0; mt < 4; mt++)
#pragma unroll
      for (int et = 0; et < 4; et++)
        acc[mt][et] = __builtin_amdgcn_mfma_f32_16x16x32_f16(af[mt], bf[et], acc[mt][et], 0, 0, 0);
  }
  float bb[4];
#pragma unroll
  for (int et = 0; et < 4; et++) bb[et] = bias[c0 + we * 64 + et * 16 + col];
  const int mbase = m0 + wm * 64 + quad * 4;
#pragma unroll
  for (int mt = 0; mt < 4; mt++)
#pragma unroll
    for (int r = 0; r < 4; r++) {
      const int m = mbase + mt * 16 + r;
#pragma unroll
      for (int et = 0; et < 4; et++)
        out[(size_t)m * DM + c0 + we * 64 + et * 16 + col] = acc[mt][et][r] + bb[et];
    }
}

extern "C" void kernel_launch(void* const* d_in, const int* in_sizes, int n_in,
                              void* d_out, int out_size, void* d_ws, size_t ws_size,
                              hipStream_t stream) {
  const float* x    = (const float*)d_in[0];
  const float* wqkv = (const float*)d_in[1];
  const float* ow   = (const float*)d_in[2];
  const float* ob   = (const float*)d_in[3];
  char* ws = (char*)d_ws;
  // guard-gapped layout (total 46.7 MB; R1 proved ws >= 64 MB usable)
  _Float16* xh    = (_Float16*)(ws);               //  8,388,608 B
  _Float16* wqkvh = (_Float16*)(ws + 8650752);     //  1,572,864 B
  _Float16* owh   = (_Float16*)(ws + 10485760);    //    524,288 B
  _Float16* qbuf  = (_Float16*)(ws + 11534336);    //  8,388,608 B
  _Float16* kbuf  = (_Float16*)(ws + 20971520);    //  8,388,608 B
  _Float16* vTb   = (_Float16*)(ws + 29360128);    //  8,388,608 B
  _Float16* ctxh  = (_Float16*)(ws + 37748736);    //  8,388,608 B
  float2*   rope  = (float2*)  (ws + 46137344);    //    524,288 B -> end 46,661,632

  zero_ws<<<2048, 256, 0, stream>>>((float4*)ws, 46661632 / 16);
  cvt_f16<<<2048, 256, 0, stream>>>(x, xh, 524288);
  cvt_f16<<<384, 256, 0, stream>>>(wqkv, wqkvh, 98304);
  cvt_f16<<<128, 256, 0, stream>>>(ow, owh, 32768);
  rope_tab<<<256, 256, 0, stream>>>(rope);
  qkv_gemm_mfma<<<dim3(64, 12), 256, 0, stream>>>(xh, wqkvh, rope, qbuf, kbuf, vTb);
  attn_win_mfma<<<dim3(32, 32), 256, 0, stream>>>(qbuf, kbuf, vTb, ctxh);
  out_gemm_mfma<<<dim3(64, 4), 256, 0, stream>>>(ctxh, owh, ob, (float*)d_out);
}